// Round 1
// 221.516 us; speedup vs baseline: 1.0162x; 1.0162x over previous
//
#include <hip/hip_runtime.h>
#include <hip/hip_bf16.h>

typedef unsigned short ushort_t;
typedef unsigned int uint_t;
typedef __attribute__((ext_vector_type(8))) short short8;
typedef __attribute__((ext_vector_type(4))) float float4v;
typedef __attribute__((ext_vector_type(4))) uint_t uint4v;

#define NLAT 2048
#define DLAT 64

// d_ws layout (ushort units): [0..127] flag area (int at byte 0), then packed weights
#define PW_BASE 128
#define PW0_OFF 0        // layer0: KT=7 -> 7*16*64*8 = 57344 ushorts
#define PW1_OFF 57344    // KT=8 -> 65536 each
#define PW2_OFF 122880
#define PW3_OFF 188416

__device__ __forceinline__ float b2f(ushort_t u) {
  union { uint_t i; float f; } v; v.i = ((uint_t)u) << 16; return v.f;
}
__device__ __forceinline__ ushort_t f2b(float f) {
  uint_t x = __float_as_uint(f);
  uint_t r = (x + 0x7fffu + ((x >> 16) & 1u)) >> 16;   // RNE
  return (ushort_t)r;
}
// HW packed f32x2 -> bf16x2 (v_cvt_pk_bf16_f32)
__device__ __forceinline__ uint_t pack2(float lo, float hi) {
  float2 t; t.x = lo; t.y = hi;
  union { __hip_bfloat162 h; uint_t u; } cv;
  cv.h = __float22bfloat162_rn(t);
  return cv.u;
}
__device__ __forceinline__ int imin(int a, int b) { return a < b ? a : b; }
__device__ __forceinline__ int imax(int a, int b) { return a > b ? a : b; }

__device__ __forceinline__ float ldv(const float* p, long i)    { return p[i]; }
__device__ __forceinline__ float ldv(const ushort_t* p, long i) { return b2f(p[i]); }
__device__ __forceinline__ void stv(float* p, long i, float v)    { p[i] = v; }
__device__ __forceinline__ void stv(ushort_t* p, long i, float v) { p[i] = f2b(v); }

__device__ __forceinline__ float4 load4f(const float* p) { return *(const float4*)p; }
__device__ __forceinline__ float4 load4f(const ushort_t* p) {
  uint2 u = *(const uint2*)p;
  float4 r;
  r.x = b2f((ushort_t)(u.x & 0xffffu)); r.y = b2f((ushort_t)(u.x >> 16));
  r.z = b2f((ushort_t)(u.y & 0xffffu)); r.w = b2f((ushort_t)(u.y >> 16));
  return r;
}

// ---------------------------------------------------------------------------
// Runtime dtype probe: flag=1 -> fp32 inputs, flag=0 -> bf16
// ---------------------------------------------------------------------------
__global__ void detect_mode(const ushort_t* __restrict__ lat, int* __restrict__ flag) {
  if (threadIdx.x == 0) *flag = 0;
  __syncthreads();
  int big = 0;
  for (int i = threadIdx.x; i < 1024; i += 64) {
    float v = b2f(lat[i]);
    if (!(fabsf(v) < 1e5f)) big = 1;
  }
  if (__any(big) && threadIdx.x == 0) *flag = 1;
}

// ---------------------------------------------------------------------------
// Pack weights as MFMA A-fragments (A = W^T, m = chan_out), sigma k-permuted
// to match the C-register order of the previous layer:
//   element j of frag(mt,kt,lane) = W[sigma][mt*16 + (lane&15)]
//   sigma = 32*kt + 16*(j>>2) + 4*(lane>>4) + (j&3)
// Layer 0: sigma indexes [sampled(192) | coord | pe(12) | pad->224].
// (unchanged from previous version — the sigma trick is reused verbatim)
// ---------------------------------------------------------------------------
template <typename TI>
__global__ void pack_w_t(const TI* __restrict__ W0, const TI* __restrict__ W1,
                         const TI* __restrict__ W2, const TI* __restrict__ W3,
                         ushort_t* __restrict__ pw, const int* __restrict__ flag, int want)
{
  if (*flag != want) return;
  int g = blockIdx.x * blockDim.x + threadIdx.x;
  if (g >= 31 * 1024) return;
  int lane = g & 63, q = lane >> 4;
  int mt   = (g >> 6) & 15;
  int ktg  = g >> 10;                       // 0..30
  const TI* W; ushort_t* dst; int kt, KT; bool isw0 = false;
  if (ktg < 7)       { W = W0; dst = pw + PW0_OFF; kt = ktg;      KT = 7; isw0 = true; }
  else if (ktg < 15) { W = W1; dst = pw + PW1_OFF; kt = ktg - 7;  KT = 8; }
  else if (ktg < 23) { W = W2; dst = pw + PW2_OFF; kt = ktg - 15; KT = 8; }
  else               { W = W3; dst = pw + PW3_OFF; kt = ktg - 23; KT = 8; }
  int col = mt * 16 + (lane & 15);
  uint_t words[4];
#pragma unroll
  for (int h = 0; h < 4; ++h) {
    ushort_t vv[2];
#pragma unroll
    for (int e = 0; e < 2; ++e) {
      int j = 2 * h + e;
      int f = 32 * kt + 16 * (j >> 2) + 4 * q + (j & 3);
      int row = f;
      if (isw0) row = (f < 192) ? (13 + f) : (f == 192 ? 0 : (f <= 204 ? f - 192 : -1));
      vv[e] = (row >= 0) ? f2b(ldv(W, (long)row * 256 + col)) : (ushort_t)0;
    }
    words[h] = (uint_t)vv[0] | ((uint_t)vv[1] << 16);
  }
  uint4 o; o.x = words[0]; o.y = words[1]; o.z = words[2]; o.w = words[3];
  *(uint4*)(dst + ((size_t)(mt * KT + kt) * 64 + lane) * 8) = o;
}

// ---------------------------------------------------------------------------
// NEW STRUCTURE: activation-stationary in LDS, weights stream L2 -> registers.
//
// Block = 4 waves, 128 points. act LDS = [pt 0..7][kt 0..7][lane 0..63][8 bf16]
// (64 KB) holding B-fragments for ALL 128 points in sigma order.
// Wave w owns output channels [64w, 64w+64) = global mt tiles 4w..4w+3.
// Per layer, wave w:
//   - streams its 4*KT A-fragments from packed global weights (1 KB each,
//     coalesced, L2-hot, double-buffered over kt) - no LDS staging at all;
//   - for each kt: 8x ds_read_b128 (B for pt=0..7), each feeding 4 MFMAs
//     -> LDS read traffic halved vs weight-in-LDS scheme (reuse 4 not 2);
//   - after a barrier, converts acc -> bias+relu+bf16 and ds_write_b128's
//     them back into act in-place. The producer mapping collapses to
//     "lane writes its own slot": kt_dst = 2*wv + (mt>>1), halves by mt&1,
//     so the stored bytes are bit-identical to the proven convert_layer.
// Barriers: 2/layer (reads-done, writes-done); no bulk vmcnt drains.
// ---------------------------------------------------------------------------
template <int KT>
__device__ __forceinline__ void run_layer_new(const ushort_t* __restrict__ pwl,
                                              float4v (&acc)[4][8],
                                              const ushort_t* __restrict__ act,
                                              int lane, int wv)
{
#pragma unroll
  for (int m = 0; m < 4; ++m)
#pragma unroll
    for (int p = 0; p < 8; ++p)
      acc[m][p] = (float4v){0.f, 0.f, 0.f, 0.f};

  // A-fragment (global mt = 4*wv + m, kt) lives at
  //   pwl + ((mt*KT + kt)*64 + lane)*8 ushorts ; per (m,kt) step = 512 ushorts.
  const ushort_t* abase = pwl + (((size_t)(4 * wv) * KT) * 64 + lane) * 8;

  short8 A0[4], A1[4];
#pragma unroll
  for (int m = 0; m < 4; ++m)
    A0[m] = *(const short8*)(abase + (size_t)(m * KT) * 512);

#pragma unroll
  for (int kt = 0; kt < KT; ++kt) {
    short8 (&Ac)[4] = (kt & 1) ? A1 : A0;   // compile-time select (kt unrolled)
    short8 (&An)[4] = (kt & 1) ? A0 : A1;
    if (kt + 1 < KT) {
#pragma unroll
      for (int m = 0; m < 4; ++m)
        An[m] = *(const short8*)(abase + (size_t)(m * KT + kt + 1) * 512);
    }
#pragma unroll
    for (int p = 0; p < 8; ++p) {
      short8 B = *(const short8*)&act[((size_t)(p * 8 + kt) * 64 + lane) * 8];
      acc[0][p] = __builtin_amdgcn_mfma_f32_16x16x32_bf16(Ac[0], B, acc[0][p], 0, 0, 0);
      acc[1][p] = __builtin_amdgcn_mfma_f32_16x16x32_bf16(Ac[1], B, acc[1][p], 0, 0, 0);
      acc[2][p] = __builtin_amdgcn_mfma_f32_16x16x32_bf16(Ac[2], B, acc[2][p], 0, 0, 0);
      acc[3][p] = __builtin_amdgcn_mfma_f32_16x16x32_bf16(Ac[3], B, acc[3][p], 0, 0, 0);
    }
  }
}

// acc -> bias+relu+bf16 -> act LDS (B-fragments of the next layer).
// Wave wv produced chans 64wv+16mt+4q+j ; those are k-chunks K=64wv+16mt+4q,
// i.e. kt_dst = 2wv + (mt>>1), half h = mt&1, lane slot = own lane. Pairing
// mt even/odd gives one contiguous conflict-free ds_write_b128 per (pair,pt).
__device__ __forceinline__ void convert_store(float4v (&acc)[4][8],
                                              ushort_t* __restrict__ act,
                                              const float* __restrict__ bwl,
                                              int lane, int wv, int q)
{
  __syncthreads();   // all waves done READING act for this layer
#pragma unroll
  for (int p2 = 0; p2 < 2; ++p2) {
    const float4 bE = *(const float4*)&bwl[wv * 64 + p2 * 32 + 4 * q];
    const float4 bO = *(const float4*)&bwl[wv * 64 + p2 * 32 + 16 + 4 * q];
    const int kt = 2 * wv + p2;
#pragma unroll
    for (int p = 0; p < 8; ++p) {
      const float4v& aE = acc[2 * p2][p];
      const float4v& aO = acc[2 * p2 + 1][p];
      uint4 o;
      o.x = pack2(fmaxf(aE[0] + bE.x, 0.f), fmaxf(aE[1] + bE.y, 0.f));
      o.y = pack2(fmaxf(aE[2] + bE.z, 0.f), fmaxf(aE[3] + bE.w, 0.f));
      o.z = pack2(fmaxf(aO[0] + bO.x, 0.f), fmaxf(aO[1] + bO.y, 0.f));
      o.w = pack2(fmaxf(aO[2] + bO.z, 0.f), fmaxf(aO[3] + bO.w, 0.f));
      *(uint4*)&act[((size_t)(p * 8 + kt) * 64 + lane) * 8] = o;
    }
  }
  __syncthreads();   // writes visible before next layer reads
}

// ---------------------------------------------------------------------------
// Fused kernel. 256 threads = 4 waves; 2 blocks/CU (LDS ~70.7 KB, regs ~
// 2 waves/SIMD as before). Weights never touch LDS; act ping-pongs in place.
// ---------------------------------------------------------------------------
template <typename TI>
__global__ __launch_bounds__(256, 2) void lisa_fused_t(
    const TI* __restrict__ coord, const TI* __restrict__ latent,
    const TI* __restrict__ bias0, const TI* __restrict__ bias1,
    const TI* __restrict__ bias2, const TI* __restrict__ bias3,
    const TI* __restrict__ W4,    const TI* __restrict__ b4,
    const ushort_t* __restrict__ pw, TI* __restrict__ out,
    const int* __restrict__ flag, int want)
{
  if (*flag != want) return;
  __shared__ __align__(16) ushort_t act[8 * 8 * 64 * 8];   // 64 KB B-fragments
  __shared__ __align__(16) float bw[4 * 256 + 256 + 1];    // biases | w4 | b4

  const int tid  = threadIdx.x;
  const int lane = tid & 63, q = lane >> 4, m15 = lane & 15;
  const int wv   = tid >> 6;                              // 0..3
  const long pbase = (long)blockIdx.x * 128 + wv * 32 + m15;  // group g adds 16

  // ---- bias/w4 table ----
  for (int i = tid; i < 1281; i += 256) {
    float v;
    if (i < 256)       v = ldv(bias0, i);
    else if (i < 512)  v = ldv(bias1, i - 256);
    else if (i < 768)  v = ldv(bias2, i - 512);
    else if (i < 1024) v = ldv(bias3, i - 768);
    else if (i < 1280) v = ldv(W4, i - 1024);
    else               v = ldv(b4, 0);
    bw[i] = v;
  }

  // ---- feature build into sigma-ordered B-frags, then store to act LDS ----
  // Wave wv owns point tiles pt = 2wv (g=0) and 2wv+1 (g=1).
  uint4v hu[7][2];
#pragma unroll
  for (int g = 0; g < 2; ++g) {
    long p = pbase + g * 16;
    float c   = ldv(coord, p);
    float ixv = c * 2048.0f - 0.5f;
    float x0f = floorf(ixv);
    float t   = ixv - x0f;
    int   x0  = (int)x0f;
    int   i0  = imin(imax(x0, 0), NLAT - 1);
    int   i1  = imin(imax(x0 + 1, 0), NLAT - 1);
    float w0 = 1.0f - t, w1 = t;
    int rows0[3] = { imax(i0 - 1, 0), i0, imin(i0 + 1, NLAT - 1) };
    int rows1[3] = { imax(i1 - 1, 0), i1, imin(i1 + 1, NLAT - 1) };
    const TI* lat = latent + (size_t)(p >> 15) * (NLAT * DLAT);
#pragma unroll
    for (int tb = 0; tb < 12; ++tb) {
      int region = tb >> 2;
      int d0 = 16 * (tb & 3) + 4 * q;
      float4 a = load4f(lat + (long)rows0[region] * DLAT + d0);
      float4 b = load4f(lat + (long)rows1[region] * DLAT + d0);
      hu[tb >> 1][g][(tb & 1) * 2 + 0] = pack2(w0 * a.x + w1 * b.x, w0 * a.y + w1 * b.y);
      hu[tb >> 1][g][(tb & 1) * 2 + 1] = pack2(w0 * a.z + w1 * b.z, w0 * a.w + w1 * b.w);
    }
    float pv[4];
#pragma unroll
    for (int s = 0; s < 4; ++s) {
      int f = 192 + 4 * q + s;
      float v = 0.0f;
      if (f == 192) v = c;
      else if (f <= 204) {
        int i = f - 193;
        float fr = (float)(1 << (i >> 1));
        float ang = c * fr;
        v = (i & 1) ? __cosf(ang) : __sinf(ang);
      }
      pv[s] = v;
    }
    hu[6][g][0] = pack2(pv[0], pv[1]);
    hu[6][g][1] = pack2(pv[2], pv[3]);
    hu[6][g][2] = 0; hu[6][g][3] = 0;

    const int pt = 2 * wv + g;
#pragma unroll
    for (int kt = 0; kt < 7; ++kt)
      *(uint4v*)&act[((size_t)(pt * 8 + kt) * 64 + lane) * 8] = hu[kt][g];
  }
  __syncthreads();   // features + bw table ready

  float4v acc[4][8];

  run_layer_new<7>(pw + PW0_OFF, acc, act, lane, wv);
  convert_store(acc, act, bw + 0 * 256, lane, wv, q);
  run_layer_new<8>(pw + PW1_OFF, acc, act, lane, wv);
  convert_store(acc, act, bw + 1 * 256, lane, wv, q);
  run_layer_new<8>(pw + PW2_OFF, acc, act, lane, wv);
  convert_store(acc, act, bw + 2 * 256, lane, wv, q);
  run_layer_new<8>(pw + PW3_OFF, acc, act, lane, wv);

  __syncthreads();   // all act reads done -> act reusable as scratch

  // ---- final: bias3+relu fused with dot against w4 (wave covers 64 chans) ----
  float psum[8];
#pragma unroll
  for (int p = 0; p < 8; ++p) psum[p] = 0.f;
#pragma unroll
  for (int m = 0; m < 4; ++m) {
    const float4 b3v = *(const float4*)&bw[3 * 256 + wv * 64 + m * 16 + 4 * q];
    const float4 w4v = *(const float4*)&bw[1024 + wv * 64 + m * 16 + 4 * q];
#pragma unroll
    for (int p = 0; p < 8; ++p) {
      float v;
      v = fmaxf(acc[m][p][0] + b3v.x, 0.f); psum[p] += v * w4v.x;
      v = fmaxf(acc[m][p][1] + b3v.y, 0.f); psum[p] += v * w4v.y;
      v = fmaxf(acc[m][p][2] + b3v.z, 0.f); psum[p] += v * w4v.z;
      v = fmaxf(acc[m][p][3] + b3v.w, 0.f); psum[p] += v * w4v.w;
    }
  }
#pragma unroll
  for (int p = 0; p < 8; ++p) {
    psum[p] += __shfl_xor(psum[p], 16, 64);
    psum[p] += __shfl_xor(psum[p], 32, 64);
  }
  float* part = (float*)act;     // [wv][128] partials, overlaid on dead act
  if (lane < 16) {
#pragma unroll
    for (int p = 0; p < 8; ++p) part[wv * 128 + p * 16 + lane] = psum[p];
  }
  __syncthreads();
  if (tid < 128) {
    float s = part[tid] + part[128 + tid] + part[256 + tid] + part[384 + tid]
            + bw[1280];
    stv(out, (long)blockIdx.x * 128 + tid, s);
  }
}

extern "C" void kernel_launch(void* const* d_in, const int* in_sizes, int n_in,
                              void* d_out, int out_size, void* d_ws, size_t ws_size,
                              hipStream_t stream) {
  int* flag = (int*)d_ws;
  ushort_t* pw = (ushort_t*)d_ws + PW_BASE;

  detect_mode<<<1, 64, 0, stream>>>((const ushort_t*)d_in[1], flag);

  // fp32-input variant (flag==1)
  pack_w_t<float><<<62, 512, 0, stream>>>(
      (const float*)d_in[2], (const float*)d_in[4], (const float*)d_in[6],
      (const float*)d_in[8], pw, flag, 1);
  lisa_fused_t<float><<<2048, 256, 0, stream>>>(
      (const float*)d_in[0], (const float*)d_in[1],
      (const float*)d_in[3], (const float*)d_in[5], (const float*)d_in[7],
      (const float*)d_in[9], (const float*)d_in[10], (const float*)d_in[11],
      pw, (float*)d_out, flag, 1);

  // bf16-input variant (flag==0)
  pack_w_t<ushort_t><<<62, 512, 0, stream>>>(
      (const ushort_t*)d_in[2], (const ushort_t*)d_in[4], (const ushort_t*)d_in[6],
      (const ushort_t*)d_in[8], pw, flag, 0);
  lisa_fused_t<ushort_t><<<2048, 256, 0, stream>>>(
      (const ushort_t*)d_in[0], (const ushort_t*)d_in[1],
      (const ushort_t*)d_in[3], (const ushort_t*)d_in[5], (const ushort_t*)d_in[7],
      (const ushort_t*)d_in[9], (const ushort_t*)d_in[10], (const ushort_t*)d_in[11],
      pw, (ushort_t*)d_out, flag, 0);
}